// Round 1
// baseline (445.802 us; speedup 1.0000x reference)
//
#include <hip/hip_runtime.h>

#define BB 4
#define CIN 32
#define COUT 32
#define TT 48
#define NN 2000
#define EE 16000
#define BT (BB*TT)

// ---- CSR build ----------------------------------------------------------

__global__ void k_count(const int* __restrict__ ei, int* __restrict__ cnt) {
    int e = blockIdx.x * blockDim.x + threadIdx.x;
    if (e < EE) atomicAdd(cnt + ei[EE + e], 1);   // dst row
}

// single block, 1024 threads: inclusive scan of cnt[0..N) -> rowptr, plus deg terms
__global__ __launch_bounds__(1024) void k_scan(const int* __restrict__ cnt,
                                               int* __restrict__ rowptr,
                                               float* __restrict__ dinv,
                                               float* __restrict__ dinv2) {
    __shared__ int buf[2048];
    int t = threadIdx.x;
    for (int i = t; i < 2048; i += 1024) buf[i] = (i < NN) ? cnt[i] : 0;
    __syncthreads();
    for (int s = 1; s < 2048; s <<= 1) {
        int i0 = t, i1 = t + 1024;
        int a0 = buf[i0] + ((i0 >= s) ? buf[i0 - s] : 0);
        int a1 = buf[i1] + ((i1 >= s) ? buf[i1 - s] : 0);
        __syncthreads();
        buf[i0] = a0; buf[i1] = a1;
        __syncthreads();
    }
    for (int i = t; i < 2048; i += 1024) {
        if (i < NN) {
            rowptr[i + 1] = buf[i];
            float deg = (float)(cnt[i] + 1);   // self-loop
            dinv[i]  = rsqrtf(deg);
            dinv2[i] = 1.0f / deg;
        }
    }
    if (t == 0) rowptr[0] = 0;
}

__global__ void k_fill(const int* __restrict__ ei, const int* __restrict__ rowptr,
                       int* __restrict__ fill, const float* __restrict__ dinv,
                       int* __restrict__ col, float* __restrict__ wedge) {
    int e = blockIdx.x * blockDim.x + threadIdx.x;
    if (e < EE) {
        int s = ei[e], d = ei[EE + e];
        int pos = rowptr[d] + atomicAdd(fill + d, 1);
        col[pos]   = s;
        wedge[pos] = dinv[s] * dinv[d];
    }
}

// ---- conv1 + relu + GCN linear -> xw [BT, N, C] -------------------------

__global__ __launch_bounds__(256) void k_conv1(const float* __restrict__ x,
                                               const float* __restrict__ w1,
                                               const float* __restrict__ b1,
                                               const float* __restrict__ gw,
                                               float* __restrict__ xw) {
    __shared__ float w1s[COUT * CIN * 3];
    __shared__ float gws[CIN * COUT];
    __shared__ float b1s[COUT];
    for (int i = threadIdx.x; i < COUT * CIN * 3; i += 256) w1s[i] = w1[i];
    for (int i = threadIdx.x; i < CIN * COUT; i += 256) gws[i] = gw[i];
    if (threadIdx.x < COUT) b1s[threadIdx.x] = b1[threadIdx.x];
    __syncthreads();

    int n = blockIdx.x * 256 + threadIdx.x;
    int t = blockIdx.y, b = blockIdx.z;
    if (n >= NN) return;

    float h[COUT];
#pragma unroll
    for (int c = 0; c < COUT; c++) h[c] = b1s[c];

    for (int k = 0; k < 3; k++) {
        int tt = t + k - 1;
        if (tt < 0 || tt >= TT) continue;
        for (int ci = 0; ci < CIN; ci++) {
            float xv = x[(((size_t)b * CIN + ci) * TT + tt) * NN + n];
            const float* wp = &w1s[ci * 3 + k];   // + c*96, wave-uniform -> LDS broadcast
#pragma unroll
            for (int c = 0; c < COUT; c++) h[c] += xv * wp[c * 96];
        }
    }

    float o[COUT];
#pragma unroll
    for (int c = 0; c < COUT; c++) o[c] = 0.f;
#pragma unroll
    for (int ci = 0; ci < CIN; ci++) {
        float hv = fmaxf(h[ci], 0.f);
#pragma unroll
        for (int c = 0; c < COUT; c++) o[c] += hv * gws[ci * COUT + c];
    }

    float4* outp = (float4*)(xw + (((size_t)(b * TT + t)) * NN + n) * COUT);
#pragma unroll
    for (int q = 0; q < 8; q++)
        outp[q] = make_float4(o[4*q], o[4*q+1], o[4*q+2], o[4*q+3]);
}

// ---- GCN aggregate: gather per (graph, node, channel) -------------------

__global__ __launch_bounds__(256) void k_agg(const float* __restrict__ xw,
                                             const int* __restrict__ rowptr,
                                             const int* __restrict__ col,
                                             const float* __restrict__ wedge,
                                             const float* __restrict__ dinv2,
                                             const float* __restrict__ gb,
                                             float* __restrict__ gbuf) {
    int c  = threadIdx.x & 31;
    int nl = threadIdx.x >> 5;
    int n  = blockIdx.x * 8 + nl;     // 250 * 8 == 2000 exact
    int g  = blockIdx.y;
    const float* xg = xw + (size_t)g * NN * COUT;

    float acc = gb[c] + dinv2[n] * xg[(size_t)n * COUT + c];
    int j1 = rowptr[n + 1];
    for (int j = rowptr[n]; j < j1; j++)
        acc += wedge[j] * xg[(size_t)col[j] * COUT + c];

    gbuf[((size_t)g * NN + n) * COUT + c] = acc;
}

// ---- conv2: [BT,N,C] -> out [B,C,T,N] -----------------------------------

__global__ __launch_bounds__(256) void k_conv2(const float* __restrict__ gbuf,
                                               const float* __restrict__ w2,
                                               const float* __restrict__ b2,
                                               float* __restrict__ out) {
    __shared__ float ws[COUT * CIN * 3];
    __shared__ float b2s[COUT];
    for (int i = threadIdx.x; i < COUT * CIN * 3; i += 256) ws[i] = w2[i];
    if (threadIdx.x < COUT) b2s[threadIdx.x] = b2[threadIdx.x];
    __syncthreads();

    int n = blockIdx.x * 256 + threadIdx.x;
    int t = blockIdx.y, b = blockIdx.z;
    if (n >= NN) return;

    float o[COUT];
#pragma unroll
    for (int c = 0; c < COUT; c++) o[c] = b2s[c];

    for (int k = 0; k < 3; k++) {
        int tt = t + k - 1;
        if (tt < 0 || tt >= TT) continue;
        const float4* gp = (const float4*)(gbuf + (((size_t)(b * TT + tt)) * NN + n) * CIN);
        float g[CIN];
#pragma unroll
        for (int q = 0; q < 8; q++) {
            float4 v = gp[q];
            g[4*q] = v.x; g[4*q+1] = v.y; g[4*q+2] = v.z; g[4*q+3] = v.w;
        }
#pragma unroll
        for (int ci = 0; ci < CIN; ci++) {
#pragma unroll
            for (int c = 0; c < COUT; c++) o[c] += g[ci] * ws[c * 96 + ci * 3 + k];
        }
    }

#pragma unroll
    for (int c = 0; c < COUT; c++)
        out[(((size_t)b * COUT + c) * TT + t) * NN + n] = o[c];
}

// ---- launch -------------------------------------------------------------

extern "C" void kernel_launch(void* const* d_in, const int* in_sizes, int n_in,
                              void* d_out, int out_size, void* d_ws, size_t ws_size,
                              hipStream_t stream) {
    const float* x     = (const float*)d_in[0];
    const int*   ei    = (const int*)d_in[1];
    const float* w1    = (const float*)d_in[2];
    const float* b1    = (const float*)d_in[3];
    const float* gcn_w = (const float*)d_in[4];
    const float* gcn_b = (const float*)d_in[5];
    const float* w2    = (const float*)d_in[6];
    const float* b2    = (const float*)d_in[7];
    float* out = (float*)d_out;

    const size_t XWB = (size_t)BT * NN * COUT * sizeof(float);  // 49.152 MB
    char* w = (char*)d_ws;
    float* xw     = (float*)w;  w += XWB;
    float* gbuf   = (float*)w;  w += XWB;
    int*   cnt    = (int*)w;    w += 8192;
    int*   fill   = (int*)w;    w += 8192;
    int*   rowptr = (int*)w;    w += 8192;
    float* dinv   = (float*)w;  w += 8192;
    float* dinv2  = (float*)w;  w += 8192;
    int*   col    = (int*)w;    w += EE * sizeof(int);
    float* wedge  = (float*)w;  w += EE * sizeof(float);

    // cnt and fill are adjacent: one memset (ws is re-poisoned to 0xAA each call)
    hipMemsetAsync(cnt, 0, 2 * 8192, stream);

    k_count<<<dim3((EE + 255) / 256), dim3(256), 0, stream>>>(ei, cnt);
    k_scan<<<dim3(1), dim3(1024), 0, stream>>>(cnt, rowptr, dinv, dinv2);
    k_fill<<<dim3((EE + 255) / 256), dim3(256), 0, stream>>>(ei, rowptr, fill, dinv, col, wedge);

    k_conv1<<<dim3((NN + 255) / 256, TT, BB), dim3(256), 0, stream>>>(x, w1, b1, gcn_w, xw);
    k_agg  <<<dim3(NN / 8, BT), dim3(256), 0, stream>>>(xw, rowptr, col, wedge, dinv2, gcn_b, gbuf);
    k_conv2<<<dim3((NN + 255) / 256, TT, BB), dim3(256), 0, stream>>>(gbuf, w2, b2, out);
}

// Round 2
// 287.781 us; speedup vs baseline: 1.5491x; 1.5491x over previous
//
#include <hip/hip_runtime.h>

#define BB 4
#define CIN 32
#define COUT 32
#define TT 48
#define NN 2000
#define EE 16000
#define BT (BB*TT)

// ---- CSR build ----------------------------------------------------------

__global__ void k_count(const int* __restrict__ ei, int* __restrict__ cnt) {
    int e = blockIdx.x * blockDim.x + threadIdx.x;
    if (e < EE) atomicAdd(cnt + ei[EE + e], 1);   // dst row
}

// single block, 1024 threads: inclusive scan of cnt[0..N) -> rowptr, plus deg terms
__global__ __launch_bounds__(1024) void k_scan(const int* __restrict__ cnt,
                                               int* __restrict__ rowptr,
                                               float* __restrict__ dinv,
                                               float* __restrict__ dinv2) {
    __shared__ int buf[2048];
    int t = threadIdx.x;
    for (int i = t; i < 2048; i += 1024) buf[i] = (i < NN) ? cnt[i] : 0;
    __syncthreads();
    for (int s = 1; s < 2048; s <<= 1) {
        int i0 = t, i1 = t + 1024;
        int a0 = buf[i0] + ((i0 >= s) ? buf[i0 - s] : 0);
        int a1 = buf[i1] + ((i1 >= s) ? buf[i1 - s] : 0);
        __syncthreads();
        buf[i0] = a0; buf[i1] = a1;
        __syncthreads();
    }
    for (int i = t; i < 2048; i += 1024) {
        if (i < NN) {
            rowptr[i + 1] = buf[i];
            float deg = (float)(cnt[i] + 1);   // self-loop
            dinv[i]  = rsqrtf(deg);
            dinv2[i] = 1.0f / deg;
        }
    }
    if (t == 0) rowptr[0] = 0;
}

__global__ void k_fill(const int* __restrict__ ei, const int* __restrict__ rowptr,
                       int* __restrict__ fill, const float* __restrict__ dinv,
                       int* __restrict__ col, float* __restrict__ wedge) {
    int e = blockIdx.x * blockDim.x + threadIdx.x;
    if (e < EE) {
        int s = ei[e], d = ei[EE + e];
        int pos = rowptr[d] + atomicAdd(fill + d, 1);
        col[pos]   = s;
        wedge[pos] = dinv[s] * dinv[d];
    }
}

// transpose conv weights [COUT][CIN][3] -> [3][CIN][COUT] so that for fixed
// (k,ci) the 32 c-values are contiguous (s_load_dwordx8-friendly).
__global__ void k_wprep(const float* __restrict__ w1, const float* __restrict__ w2,
                        float* __restrict__ w1t, float* __restrict__ w2t) {
    int i = blockIdx.x * blockDim.x + threadIdx.x;   // 3072
    if (i >= COUT * CIN * 3) return;
    int c = i / (CIN * 3), r = i % (CIN * 3);
    int ci = r / 3, k = r % 3;
    w1t[(k * CIN + ci) * COUT + c] = w1[i];
    w2t[(k * CIN + ci) * COUT + c] = w2[i];
}

// ---- conv1 + relu + GCN linear -> xw [BT, N, C] -------------------------
// Weights read directly from global at wave-uniform indices -> scalar loads.

__global__ __launch_bounds__(256) void k_conv1(const float* __restrict__ x,
                                               const float* __restrict__ w1t,
                                               const float* __restrict__ b1,
                                               const float* __restrict__ gw,
                                               float* __restrict__ xw) {
    int n = blockIdx.x * 256 + threadIdx.x;
    int t = blockIdx.y, b = blockIdx.z;
    if (n >= NN) return;

    float h[COUT];
#pragma unroll
    for (int c = 0; c < COUT; c++) h[c] = b1[c];

    for (int k = 0; k < 3; k++) {
        int tt = t + k - 1;
        if (tt < 0 || tt >= TT) continue;
        const float* xp = x + (((size_t)b * CIN) * TT + tt) * NN + n;
        const float* wp = w1t + k * CIN * COUT;
        for (int ci = 0; ci < CIN; ci++) {
            float xv = xp[(size_t)ci * TT * NN];
#pragma unroll
            for (int c = 0; c < COUT; c++) h[c] += xv * wp[ci * COUT + c];
        }
    }

    float o[COUT];
#pragma unroll
    for (int c = 0; c < COUT; c++) o[c] = 0.f;
#pragma unroll
    for (int ci = 0; ci < CIN; ci++) {
        float hv = fmaxf(h[ci], 0.f);
#pragma unroll
        for (int c = 0; c < COUT; c++) o[c] += hv * gw[ci * COUT + c];
    }

    float4* outp = (float4*)(xw + (((size_t)(b * TT + t)) * NN + n) * COUT);
#pragma unroll
    for (int q = 0; q < 8; q++)
        outp[q] = make_float4(o[4*q], o[4*q+1], o[4*q+2], o[4*q+3]);
}

// ---- GCN aggregate ------------------------------------------------------
// 2 nodes/thread + 4-edge batching: up to 8 independent gathers in flight.
// 1D grid XCD-swizzled: all blocks of one graph land on one XCD (L2 locality).

#define AGG_GATHER4(J, ACC)                                                    \
    {                                                                          \
        int i0 = col[J], i1 = col[J+1], i2 = col[J+2], i3 = col[J+3];          \
        float w0 = wedge[J], w1_ = wedge[J+1], w2_ = wedge[J+2], w3 = wedge[J+3];\
        float v0 = xg[(size_t)i0 * 32 + c];                                    \
        float v1 = xg[(size_t)i1 * 32 + c];                                    \
        float v2 = xg[(size_t)i2 * 32 + c];                                    \
        float v3 = xg[(size_t)i3 * 32 + c];                                    \
        ACC += w0 * v0 + w1_ * v1 + w2_ * v2 + w3 * v3;                        \
    }

__global__ __launch_bounds__(256) void k_agg(const float* __restrict__ xw,
                                             const int* __restrict__ rowptr,
                                             const int* __restrict__ col,
                                             const float* __restrict__ wedge,
                                             const float* __restrict__ dinv2,
                                             const float* __restrict__ gb,
                                             float* __restrict__ gbuf) {
    // grid = 24000 blocks: 8 xcd-slots x 24 graphs x 125 node-chunks of 16
    int bid = blockIdx.x;
    int xcd = bid & 7;
    int q   = bid >> 3;             // 0..2999
    int g   = (q / 125) * 8 + xcd;  // graph
    int nch = q % 125;              // node chunk
    int c   = threadIdx.x & 31;
    int nl  = threadIdx.x >> 5;     // 0..7
    int n0  = nch * 16 + nl;
    int n1  = n0 + 8;
    const float* xg = xw + (size_t)g * NN * COUT;

    float bias = gb[c];
    float accA = bias + dinv2[n0] * xg[(size_t)n0 * 32 + c];
    float accB = bias + dinv2[n1] * xg[(size_t)n1 * 32 + c];
    int jA = rowptr[n0], eA = rowptr[n0 + 1];
    int jB = rowptr[n1], eB = rowptr[n1 + 1];

    while (jA + 4 <= eA && jB + 4 <= eB) {
        AGG_GATHER4(jA, accA)
        AGG_GATHER4(jB, accB)
        jA += 4; jB += 4;
    }
    while (jA + 4 <= eA) { AGG_GATHER4(jA, accA) jA += 4; }
    while (jB + 4 <= eB) { AGG_GATHER4(jB, accB) jB += 4; }
    for (; jA < eA; jA++) accA += wedge[jA] * xg[(size_t)col[jA] * 32 + c];
    for (; jB < eB; jB++) accB += wedge[jB] * xg[(size_t)col[jB] * 32 + c];

    gbuf[((size_t)g * NN + n0) * 32 + c] = accA;
    gbuf[((size_t)g * NN + n1) * 32 + c] = accB;
}

// ---- conv2: [BT,N,C] -> out [B,C,T,N] -----------------------------------

__global__ __launch_bounds__(256) void k_conv2(const float* __restrict__ gbuf,
                                               const float* __restrict__ w2t,
                                               const float* __restrict__ b2,
                                               float* __restrict__ out) {
    int n = blockIdx.x * 256 + threadIdx.x;
    int t = blockIdx.y, b = blockIdx.z;
    if (n >= NN) return;

    float o[COUT];
#pragma unroll
    for (int c = 0; c < COUT; c++) o[c] = b2[c];

    for (int k = 0; k < 3; k++) {
        int tt = t + k - 1;
        if (tt < 0 || tt >= TT) continue;
        const float4* gp = (const float4*)(gbuf + (((size_t)(b * TT + tt)) * NN + n) * CIN);
        const float* wp = w2t + k * CIN * COUT;
        float gv[CIN];
#pragma unroll
        for (int qq = 0; qq < 8; qq++) {
            float4 v = gp[qq];
            gv[4*qq] = v.x; gv[4*qq+1] = v.y; gv[4*qq+2] = v.z; gv[4*qq+3] = v.w;
        }
#pragma unroll
        for (int ci = 0; ci < CIN; ci++) {
#pragma unroll
            for (int c = 0; c < COUT; c++) o[c] += gv[ci] * wp[ci * COUT + c];
        }
    }

#pragma unroll
    for (int c = 0; c < COUT; c++)
        out[(((size_t)b * COUT + c) * TT + t) * NN + n] = o[c];
}

// ---- launch -------------------------------------------------------------

extern "C" void kernel_launch(void* const* d_in, const int* in_sizes, int n_in,
                              void* d_out, int out_size, void* d_ws, size_t ws_size,
                              hipStream_t stream) {
    const float* x     = (const float*)d_in[0];
    const int*   ei    = (const int*)d_in[1];
    const float* w1    = (const float*)d_in[2];
    const float* b1    = (const float*)d_in[3];
    const float* gcn_w = (const float*)d_in[4];
    const float* gcn_b = (const float*)d_in[5];
    const float* w2    = (const float*)d_in[6];
    const float* b2    = (const float*)d_in[7];
    float* out = (float*)d_out;

    const size_t XWB = (size_t)BT * NN * COUT * sizeof(float);  // 49.152 MB
    char* w = (char*)d_ws;
    float* xw     = (float*)w;  w += XWB;
    float* gbuf   = (float*)w;  w += XWB;
    int*   cnt    = (int*)w;    w += 8192;
    int*   fill   = (int*)w;    w += 8192;
    int*   rowptr = (int*)w;    w += 8192;
    float* dinv   = (float*)w;  w += 8192;
    float* dinv2  = (float*)w;  w += 8192;
    int*   col    = (int*)w;    w += EE * sizeof(int);
    float* wedge  = (float*)w;  w += EE * sizeof(float);
    float* w1t    = (float*)w;  w += COUT * CIN * 3 * sizeof(float);
    float* w2t    = (float*)w;  w += COUT * CIN * 3 * sizeof(float);

    // cnt and fill are adjacent: one memset (ws is re-poisoned to 0xAA each call)
    hipMemsetAsync(cnt, 0, 2 * 8192, stream);

    k_count<<<dim3((EE + 255) / 256), dim3(256), 0, stream>>>(ei, cnt);
    k_scan<<<dim3(1), dim3(1024), 0, stream>>>(cnt, rowptr, dinv, dinv2);
    k_fill<<<dim3((EE + 255) / 256), dim3(256), 0, stream>>>(ei, rowptr, fill, dinv, col, wedge);
    k_wprep<<<dim3((COUT * CIN * 3 + 255) / 256), dim3(256), 0, stream>>>(w1, w2, w1t, w2t);

    k_conv1<<<dim3((NN + 255) / 256, TT, BB), dim3(256), 0, stream>>>(x, w1t, b1, gcn_w, xw);
    k_agg  <<<dim3(24000), dim3(256), 0, stream>>>(xw, rowptr, col, wedge, dinv2, gcn_b, gbuf);
    k_conv2<<<dim3((NN + 255) / 256, TT, BB), dim3(256), 0, stream>>>(gbuf, w2t, b2, out);
}